// Round 2
// baseline (730.975 us; speedup 1.0000x reference)
//
#include <hip/hip_runtime.h>

// Problem constants: B=4, S=T=16, DIM=512, H=W=32, HEADS=8, dh=64
// q,k,v: [4,16,512,32,32] fp32 (33,554,432 elems each); Wq/Wk/Wv: [512,512] fp32.
// out: [4,16,512,32,32] fp32.
//
// Pipeline:
//  k_means : qm_raw[b,s,c], km_raw[b,t,c] = mean over 1024-pixel plane
//  k_trans : vT[b,t][m][c] = bf16(v[b,t,c,m])   (k-major B operand for GEMM)
//  k_attn  : Wv->bf16; qh/kh projections; attn[b,h,s,t] = softmax(qh.kh)
//  k_gemm  : VP[b,t][d][m] = sum_c Wv[d,c]*v[b,t,c,m]  (bf16 MFMA, fp32 out -> d_out)
//  k_mix   : in-place on d_out: out[b,s,d,p] = sum_t attn[b,h(d),s,t]*VP[b,t,d,m(p)]
//            with the 32x32 spatial transpose m(p) = (p%32)*32 + p/32.

__device__ __forceinline__ unsigned short f2bf(float f) {
  union { float f; unsigned int u; } x; x.f = f;
  unsigned int r = x.u + 0x7fffu + ((x.u >> 16) & 1u);  // round-to-nearest-even
  return (unsigned short)(r >> 16);
}

typedef __attribute__((ext_vector_type(8))) __bf16 bf16x8;
typedef __attribute__((ext_vector_type(4))) float f32x4;

// ---------------------------------------------------------------- k_means
// grid 16384 x 256. Blocks [0,8192): q -> qm ; [8192,16384): k -> km.
// One wave per channel-plane (1024 contiguous floats).
__global__ __launch_bounds__(256) void k_means(const float* __restrict__ q,
                                               const float* __restrict__ k,
                                               float* __restrict__ qm,
                                               float* __restrict__ km) {
  int n = blockIdx.x;
  const float* src = (n < 8192) ? q : k;
  float* dst = (n < 8192) ? qm : km;
  int chan = (n & 8191) * 4 + (threadIdx.x >> 6);
  int lane = threadIdx.x & 63;
  const float4* p = (const float4*)(src + (size_t)chan * 1024);
  float s = 0.f;
#pragma unroll
  for (int i = 0; i < 4; ++i) {
    float4 f = p[i * 64 + lane];
    s += f.x + f.y + f.z + f.w;
  }
#pragma unroll
  for (int off = 32; off > 0; off >>= 1) s += __shfl_down(s, off);
  if (lane == 0) dst[chan] = s * (1.0f / 1024.0f);
}

// ---------------------------------------------------------------- k_trans
// grid (16 m-tiles, 8 c-tiles, 64 bt) x 256. 64x64 tile transpose + fp32->bf16.
__global__ __launch_bounds__(256) void k_trans(const float* __restrict__ v,
                                               unsigned short* __restrict__ vT) {
  int tid = threadIdx.x;
  int m0 = blockIdx.x * 64, c0 = blockIdx.y * 64, bt = blockIdx.z;
  __shared__ float ls[64 * 65];
  const float* src = v + (size_t)bt * 524288;
#pragma unroll
  for (int p = 0; p < 4; ++p) {
    int r = p * 16 + (tid >> 4);
    int mm4 = (tid & 15) * 4;
    float4 f = *(const float4*)&src[(size_t)(c0 + r) * 1024 + m0 + mm4];
    ls[r * 65 + mm4 + 0] = f.x;
    ls[r * 65 + mm4 + 1] = f.y;
    ls[r * 65 + mm4 + 2] = f.z;
    ls[r * 65 + mm4 + 3] = f.w;
  }
  __syncthreads();
  unsigned short* dst = vT + (size_t)bt * 524288;
#pragma unroll
  for (int p = 0; p < 2; ++p) {
    int mm = p * 32 + (tid >> 3);
    int cr8 = (tid & 7) * 8;
    unsigned int w[4];
#pragma unroll
    for (int e = 0; e < 4; ++e) {
      unsigned short lo = f2bf(ls[(cr8 + 2 * e + 0) * 65 + mm]);
      unsigned short hi = f2bf(ls[(cr8 + 2 * e + 1) * 65 + mm]);
      w[e] = (unsigned int)lo | ((unsigned int)hi << 16);
    }
    uint4 pk = {w[0], w[1], w[2], w[3]};
    *(uint4*)&dst[(size_t)(m0 + mm) * 512 + c0 + cr8] = pk;
  }
}

// ---------------------------------------------------------------- k_attn
// grid 32 (b*8+h) x 256. Also converts Wv -> bf16.
__global__ __launch_bounds__(256) void k_attn(const float* __restrict__ qm,
                                              const float* __restrict__ km,
                                              const float* __restrict__ Wq,
                                              const float* __restrict__ Wk,
                                              const float* __restrict__ Wv,
                                              unsigned short* __restrict__ Wv_bf,
                                              float* __restrict__ attn) {
  int tid = threadIdx.x;
  int b = blockIdx.x >> 3, h = blockIdx.x & 7;
  // Wv -> bf16 (65536 float4 across 8192 threads)
  {
    const float4* s4 = (const float4*)Wv;
#pragma unroll
    for (int i = 0; i < 8; ++i) {
      int idx = blockIdx.x * 256 + tid + i * 8192;
      float4 f = s4[idx];
      ushort4 u;
      u.x = f2bf(f.x); u.y = f2bf(f.y); u.z = f2bf(f.z); u.w = f2bf(f.w);
      *(ushort4*)&Wv_bf[(size_t)idx * 4] = u;
    }
  }
  __shared__ float WS[64 * 65];
  __shared__ float xS[16 * 64];
  __shared__ float qhS[16 * 65];
  __shared__ float khS[16 * 65];
  __shared__ float lg[16 * 17];
  int j = tid & 63, so = tid >> 6;
  float acc[4];

  // ---- qh = (qm @ Wq.T) * scale ----
  acc[0] = acc[1] = acc[2] = acc[3] = 0.f;
  for (int c0 = 0; c0 < 512; c0 += 64) {
    __syncthreads();
#pragma unroll
    for (int p = 0; p < 4; ++p) {
      int r = p * 16 + (tid >> 4);
      int c4 = (tid & 15) * 4;
      float4 f = *(const float4*)&Wq[(size_t)(h * 64 + r) * 512 + c0 + c4];
      WS[r * 65 + c4 + 0] = f.x; WS[r * 65 + c4 + 1] = f.y;
      WS[r * 65 + c4 + 2] = f.z; WS[r * 65 + c4 + 3] = f.w;
    }
    {
      int s = tid >> 4;
      int c4 = (tid & 15) * 4;
      float4 f = *(const float4*)&qm[(size_t)(b * 16 + s) * 512 + c0 + c4];
      xS[s * 64 + c4 + 0] = f.x; xS[s * 64 + c4 + 1] = f.y;
      xS[s * 64 + c4 + 2] = f.z; xS[s * 64 + c4 + 3] = f.w;
    }
    __syncthreads();
    for (int cc = 0; cc < 64; ++cc) {
      float wv = WS[j * 65 + cc];
#pragma unroll
      for (int o = 0; o < 4; ++o) acc[o] += xS[(o * 4 + so) * 64 + cc] * wv;
    }
  }
#pragma unroll
  for (int o = 0; o < 4; ++o) qhS[(o * 4 + so) * 65 + j] = acc[o] * 0.125f;

  // ---- kh = km @ Wk.T ----
  acc[0] = acc[1] = acc[2] = acc[3] = 0.f;
  for (int c0 = 0; c0 < 512; c0 += 64) {
    __syncthreads();
#pragma unroll
    for (int p = 0; p < 4; ++p) {
      int r = p * 16 + (tid >> 4);
      int c4 = (tid & 15) * 4;
      float4 f = *(const float4*)&Wk[(size_t)(h * 64 + r) * 512 + c0 + c4];
      WS[r * 65 + c4 + 0] = f.x; WS[r * 65 + c4 + 1] = f.y;
      WS[r * 65 + c4 + 2] = f.z; WS[r * 65 + c4 + 3] = f.w;
    }
    {
      int s = tid >> 4;
      int c4 = (tid & 15) * 4;
      float4 f = *(const float4*)&km[(size_t)(b * 16 + s) * 512 + c0 + c4];
      xS[s * 64 + c4 + 0] = f.x; xS[s * 64 + c4 + 1] = f.y;
      xS[s * 64 + c4 + 2] = f.z; xS[s * 64 + c4 + 3] = f.w;
    }
    __syncthreads();
    for (int cc = 0; cc < 64; ++cc) {
      float wv = WS[j * 65 + cc];
#pragma unroll
      for (int o = 0; o < 4; ++o) acc[o] += xS[(o * 4 + so) * 64 + cc] * wv;
    }
  }
#pragma unroll
  for (int o = 0; o < 4; ++o) khS[(o * 4 + so) * 65 + j] = acc[o];
  __syncthreads();

  // logits + softmax
  {
    int s = tid >> 4, t = tid & 15;
    float a = 0.f;
    for (int jj = 0; jj < 64; ++jj) a += qhS[s * 65 + jj] * khS[t * 65 + jj];
    lg[s * 17 + t] = a;
  }
  __syncthreads();
  if (tid < 16) {
    int s = tid;
    float mx = -1e30f;
#pragma unroll
    for (int t = 0; t < 16; ++t) mx = fmaxf(mx, lg[s * 17 + t]);
    float e[16], sum = 0.f;
#pragma unroll
    for (int t = 0; t < 16; ++t) { e[t] = __expf(lg[s * 17 + t] - mx); sum += e[t]; }
    float inv = 1.0f / sum;
#pragma unroll
    for (int t = 0; t < 16; ++t) attn[((b * 8 + h) * 16 + s) * 16 + t] = e[t] * inv;
  }
}

// ---------------------------------------------------------------- k_gemm
// grid (8 m-tiles, 4 d-tiles, 64 bt) x 256. m97 structure: 128x128 tile, BK=32,
// 4 waves (2x2 of 64x64), 16x16x32 bf16 MFMA, global_load_lds 16B staging.
// VP[d][m] = sum_c Wv[d][c] * vT[m][c]  -> fp32 into d_out.
__global__ __launch_bounds__(256) void k_gemm(const unsigned short* __restrict__ Wv_bf,
                                              const unsigned short* __restrict__ vT,
                                              float* __restrict__ VP) {
  int tid = threadIdx.x;
  int bx = blockIdx.x, by = blockIdx.y, bz = blockIdx.z;
  __shared__ __align__(16) unsigned short As[128 * 32];
  __shared__ __align__(16) unsigned short Bs[128 * 32];
  const unsigned short* Ag = Wv_bf + (size_t)(by * 128) * 512;
  const unsigned short* Bg = vT + (size_t)bz * 524288 + (size_t)(bx * 128) * 512;
  int r = tid >> 2;           // 0..63 (staging row)
  int c8 = (tid & 3) * 8;     // k offset within BK=32
  int lane = tid & 63, wave = tid >> 6;
  int wd = wave >> 1, wm = wave & 1;
  int l15 = lane & 15, quad = lane >> 4;

  f32x4 acc[4][4];
#pragma unroll
  for (int i = 0; i < 4; ++i)
#pragma unroll
    for (int j = 0; j < 4; ++j) acc[i][j] = (f32x4){0.f, 0.f, 0.f, 0.f};

  for (int kk = 0; kk < 16; ++kk) {
    int c0 = kk * 32;
    if (kk) __syncthreads();
    __builtin_amdgcn_global_load_lds(
        (const __attribute__((address_space(1))) void*)(Ag + (size_t)r * 512 + c0 + c8),
        (__attribute__((address_space(3))) void*)&As[tid * 8], 16, 0, 0);
    __builtin_amdgcn_global_load_lds(
        (const __attribute__((address_space(1))) void*)(Ag + (size_t)(r + 64) * 512 + c0 + c8),
        (__attribute__((address_space(3))) void*)&As[2048 + tid * 8], 16, 0, 0);
    __builtin_amdgcn_global_load_lds(
        (const __attribute__((address_space(1))) void*)(Bg + (size_t)r * 512 + c0 + c8),
        (__attribute__((address_space(3))) void*)&Bs[tid * 8], 16, 0, 0);
    __builtin_amdgcn_global_load_lds(
        (const __attribute__((address_space(1))) void*)(Bg + (size_t)(r + 64) * 512 + c0 + c8),
        (__attribute__((address_space(3))) void*)&Bs[2048 + tid * 8], 16, 0, 0);
    __syncthreads();  // compiler drains vmcnt before s_barrier (m97-verified)

    bf16x8 af[4], bfr[4];
#pragma unroll
    for (int i = 0; i < 4; ++i)
      af[i] = *(const bf16x8*)&As[(wd * 64 + i * 16 + l15) * 32 + quad * 8];
#pragma unroll
    for (int j = 0; j < 4; ++j)
      bfr[j] = *(const bf16x8*)&Bs[(wm * 64 + j * 16 + l15) * 32 + quad * 8];
#pragma unroll
    for (int i = 0; i < 4; ++i)
#pragma unroll
      for (int j = 0; j < 4; ++j)
        acc[i][j] = __builtin_amdgcn_mfma_f32_16x16x32_bf16(af[i], bfr[j], acc[i][j], 0, 0, 0);
  }

  float* outp = VP + (size_t)bz * 524288;
#pragma unroll
  for (int i = 0; i < 4; ++i) {
#pragma unroll
    for (int j = 0; j < 4; ++j) {
      int m = bx * 128 + wm * 64 + j * 16 + l15;
#pragma unroll
      for (int rr = 0; rr < 4; ++rr) {
        int d = by * 128 + wd * 64 + i * 16 + quad * 4 + rr;  // C/D: row=quad*4+reg, col=lane&15
        outp[(size_t)d * 1024 + m] = acc[i][j][rr];
      }
    }
  }
}

// ---------------------------------------------------------------- k_mix (v2)
// grid 2048 (b*512+d) x 256. In-place on d_out.
// Register-blocked: each thread covers 4 s x 16 contiguous p (attn hoisted to
// registers; vp reads cut 1088 -> ~336 LDS insts/thread). t chunked in halves:
// LDS 8 x 1152 fp32 (~37 KB) -> 4 blocks/CU. Pad +4 floats per 32-group keeps
// staging ds_write_b128 16B-aligned; strided reads are exact 2-way (free).
__global__ __launch_bounds__(256, 4) void k_mix(float* __restrict__ out,
                                                const float* __restrict__ attn) {
  int blk = blockIdx.x;
  int b = blk >> 9, d = blk & 511, h = d >> 6;
  int tid = threadIdx.x;
  __shared__ float VPs[8 * 1152];
  __shared__ float attnS[256];
  attnS[tid] = attn[(b * 8 + h) * 256 + tid];

  int l = tid & 63, sg = tid >> 6;
  int p0 = l * 16;                 // 16 contiguous output pixels
  // m(p) = (p%32)*32 + p/32 ; padded index mi = m + 4*(m>>5) = (p%32)*36 + p/32
  int phalf = 16 * (l & 1);        // p%32 base for this thread's chunk
  int pdiv = l >> 1;               // p/32 (constant across the 16-chunk)
  int m0 = tid * 4;                // staging: 4 contiguous m
  int miw = m0 + 4 * (m0 >> 5);    // padded, 16B-aligned

  size_t base = ((size_t)(b * 16) * 512 + d) * 1024;  // row (b, t=0, d)
  float res[4][16];
#pragma unroll
  for (int si = 0; si < 4; ++si)
#pragma unroll
    for (int u = 0; u < 16; ++u) res[si][u] = 0.f;

  for (int ch = 0; ch < 2; ++ch) {
    if (ch) __syncthreads();  // drain chunk-0 reads before restaging
#pragma unroll
    for (int t = 0; t < 8; ++t) {
      float4 f = *(const float4*)&out[base + (size_t)(ch * 8 + t) * 524288 + m0];
      *(float4*)&VPs[t * 1152 + miw] = f;
    }
    __syncthreads();
#pragma unroll
    for (int t = 0; t < 8; ++t) {
      float a4[4];
#pragma unroll
      for (int si = 0; si < 4; ++si) a4[si] = attnS[(sg * 4 + si) * 16 + ch * 8 + t];
      float vp[16];
#pragma unroll
      for (int u = 0; u < 16; ++u) vp[u] = VPs[t * 1152 + (phalf + u) * 36 + pdiv];
#pragma unroll
      for (int si = 0; si < 4; ++si)
#pragma unroll
        for (int u = 0; u < 16; ++u) res[si][u] += a4[si] * vp[u];
    }
  }

  // All global reads of this block's 16 rows are complete; write the 16 s-rows
  // (same address set -> in-place safe, disjoint across blocks).
#pragma unroll
  for (int si = 0; si < 4; ++si) {
    int s = sg * 4 + si;
    float* op = &out[((size_t)(b * 16 + s) * 512 + d) * 1024 + p0];
#pragma unroll
    for (int e = 0; e < 4; ++e) {
      float4 f = {res[si][e * 4 + 0], res[si][e * 4 + 1],
                  res[si][e * 4 + 2], res[si][e * 4 + 3]};
      *(float4*)&op[e * 4] = f;
    }
  }
}

// ---------------------------------------------------------------- launch
extern "C" void kernel_launch(void* const* d_in, const int* in_sizes, int n_in,
                              void* d_out, int out_size, void* d_ws, size_t ws_size,
                              hipStream_t stream) {
  const float* q  = (const float*)d_in[0];
  const float* k  = (const float*)d_in[1];
  const float* v  = (const float*)d_in[2];
  const float* Wq = (const float*)d_in[3];
  const float* Wk = (const float*)d_in[4];
  const float* Wv = (const float*)d_in[5];
  // heads (d_in[6]) is the constant 8 — baked in.

  char* ws = (char*)d_ws;
  unsigned short* vT    = (unsigned short*)ws;                 // 67,108,864 B
  unsigned short* Wv_bf = (unsigned short*)(ws + 67108864);    //    524,288 B
  float* qm   = (float*)(ws + 67633152);                       //    131,072 B
  float* km   = (float*)(ws + 67764224);                       //    131,072 B
  float* attn = (float*)(ws + 67895296);                       //     32,768 B
  float* out  = (float*)d_out;

  k_means<<<16384, 256, 0, stream>>>(q, k, qm, km);
  k_trans<<<dim3(16, 8, 64), 256, 0, stream>>>(v, vT);
  k_attn<<<32, 256, 0, stream>>>(qm, km, Wq, Wk, Wv, Wv_bf, attn);
  k_gemm<<<dim3(8, 4, 64), 256, 0, stream>>>(Wv_bf, vT, out);
  k_mix<<<2048, 256, 0, stream>>>(out, attn);
}

// Round 3
// 534.018 us; speedup vs baseline: 1.3688x; 1.3688x over previous
//
#include <hip/hip_runtime.h>

// Problem constants: B=4, S=T=16, DIM=512, H=W=32, HEADS=8, dh=64
// q,k,v: [4,16,512,32,32] fp32 (33,554,432 elems each); Wq/Wk/Wv: [512,512] fp32.
// out: [4,16,512,32,32] fp32.
//
// Pipeline (v3: spatial transpose folded into k_trans row permutation):
//  k_means : qm[b,s,c], km[b,t,c] = mean over 1024-pixel plane
//  k_trans : vT[b,t][r][c] = bf16(v[b,t,c,m(r)]), m(r)=(r%32)*32+r/32 (involution)
//            -> GEMM "m" axis is already output-pixel order
//  k_attn  : Wv->bf16; attnT[b,h][t][s] = softmax over t of (qh.kh)
//  k_gemm  : VP[b,t][d][p] = sum_c Wv[d,c]*vT[t,p,c]  (bf16 MFMA, fp32 -> d_out)
//  k_mix   : in-place on d_out, no LDS: out[b,s,d,p] = sum_t attnT[t][s]*VP[b,t,d,p]

__device__ __forceinline__ unsigned short f2bf(float f) {
  union { float f; unsigned int u; } x; x.f = f;
  unsigned int r = x.u + 0x7fffu + ((x.u >> 16) & 1u);  // round-to-nearest-even
  return (unsigned short)(r >> 16);
}

typedef __attribute__((ext_vector_type(8))) __bf16 bf16x8;
typedef __attribute__((ext_vector_type(4))) float f32x4;

// ---------------------------------------------------------------- k_means
// grid 16384 x 256. Blocks [0,8192): q -> qm ; [8192,16384): k -> km.
__global__ __launch_bounds__(256) void k_means(const float* __restrict__ q,
                                               const float* __restrict__ k,
                                               float* __restrict__ qm,
                                               float* __restrict__ km) {
  int n = blockIdx.x;
  const float* src = (n < 8192) ? q : k;
  float* dst = (n < 8192) ? qm : km;
  int chan = (n & 8191) * 4 + (threadIdx.x >> 6);
  int lane = threadIdx.x & 63;
  const float4* p = (const float4*)(src + (size_t)chan * 1024);
  float s = 0.f;
#pragma unroll
  for (int i = 0; i < 4; ++i) {
    float4 f = p[i * 64 + lane];
    s += f.x + f.y + f.z + f.w;
  }
#pragma unroll
  for (int off = 32; off > 0; off >>= 1) s += __shfl_down(s, off);
  if (lane == 0) dst[chan] = s * (1.0f / 1024.0f);
}

// ---------------------------------------------------------------- k_trans
// grid (16 m-tiles, 8 c-tiles, 64 bt) x 256. 64x64 tile transpose + fp32->bf16.
// Row permutation: pixel x lands in vT row r = m(x) = (x%32)*32 + x/32, so the
// GEMM's output column index is already the final output pixel index.
// Each store is 8 lanes x 16 B = 128 B contiguous, 128 B-aligned (full line).
__global__ __launch_bounds__(256) void k_trans(const float* __restrict__ v,
                                               unsigned short* __restrict__ vT) {
  int tid = threadIdx.x;
  int m0 = blockIdx.x * 64, c0 = blockIdx.y * 64, bt = blockIdx.z;
  __shared__ float ls[64 * 65];
  const float* src = v + (size_t)bt * 524288;
#pragma unroll
  for (int p = 0; p < 4; ++p) {
    int r = p * 16 + (tid >> 4);
    int mm4 = (tid & 15) * 4;
    float4 f = *(const float4*)&src[(size_t)(c0 + r) * 1024 + m0 + mm4];
    ls[r * 65 + mm4 + 0] = f.x;
    ls[r * 65 + mm4 + 1] = f.y;
    ls[r * 65 + mm4 + 2] = f.z;
    ls[r * 65 + mm4 + 3] = f.w;
  }
  __syncthreads();
  unsigned short* dst = vT + (size_t)bt * 524288;
#pragma unroll
  for (int p = 0; p < 2; ++p) {
    int mm = p * 32 + (tid >> 3);
    int cr8 = (tid & 7) * 8;
    unsigned int w[4];
#pragma unroll
    for (int e = 0; e < 4; ++e) {
      unsigned short lo = f2bf(ls[(cr8 + 2 * e + 0) * 65 + mm]);
      unsigned short hi = f2bf(ls[(cr8 + 2 * e + 1) * 65 + mm]);
      w[e] = (unsigned int)lo | ((unsigned int)hi << 16);
    }
    uint4 pk = {w[0], w[1], w[2], w[3]};
    int x = m0 + mm;                           // memory pixel index
    int rr = ((x & 31) << 5) | (x >> 5);       // permuted destination row
    *(uint4*)&dst[(size_t)rr * 512 + c0 + cr8] = pk;
  }
}

// ---------------------------------------------------------------- k_attn
// grid 32 (b*8+h) x 256. Also converts Wv -> bf16. attn stored [t][s].
__global__ __launch_bounds__(256) void k_attn(const float* __restrict__ qm,
                                              const float* __restrict__ km,
                                              const float* __restrict__ Wq,
                                              const float* __restrict__ Wk,
                                              const float* __restrict__ Wv,
                                              unsigned short* __restrict__ Wv_bf,
                                              float* __restrict__ attnT) {
  int tid = threadIdx.x;
  int b = blockIdx.x >> 3, h = blockIdx.x & 7;
  // Wv -> bf16 (65536 float4 across 8192 threads)
  {
    const float4* s4 = (const float4*)Wv;
#pragma unroll
    for (int i = 0; i < 8; ++i) {
      int idx = blockIdx.x * 256 + tid + i * 8192;
      float4 f = s4[idx];
      ushort4 u;
      u.x = f2bf(f.x); u.y = f2bf(f.y); u.z = f2bf(f.z); u.w = f2bf(f.w);
      *(ushort4*)&Wv_bf[(size_t)idx * 4] = u;
    }
  }
  __shared__ float WS[64 * 65];
  __shared__ float xS[16 * 64];
  __shared__ float qhS[16 * 65];
  __shared__ float khS[16 * 65];
  __shared__ float lg[16 * 17];
  int j = tid & 63, so = tid >> 6;
  float acc[4];

  // ---- qh = (qm @ Wq.T) * scale ----
  acc[0] = acc[1] = acc[2] = acc[3] = 0.f;
  for (int c0 = 0; c0 < 512; c0 += 64) {
    __syncthreads();
#pragma unroll
    for (int p = 0; p < 4; ++p) {
      int r = p * 16 + (tid >> 4);
      int c4 = (tid & 15) * 4;
      float4 f = *(const float4*)&Wq[(size_t)(h * 64 + r) * 512 + c0 + c4];
      WS[r * 65 + c4 + 0] = f.x; WS[r * 65 + c4 + 1] = f.y;
      WS[r * 65 + c4 + 2] = f.z; WS[r * 65 + c4 + 3] = f.w;
    }
    {
      int s = tid >> 4;
      int c4 = (tid & 15) * 4;
      float4 f = *(const float4*)&qm[(size_t)(b * 16 + s) * 512 + c0 + c4];
      xS[s * 64 + c4 + 0] = f.x; xS[s * 64 + c4 + 1] = f.y;
      xS[s * 64 + c4 + 2] = f.z; xS[s * 64 + c4 + 3] = f.w;
    }
    __syncthreads();
    for (int cc = 0; cc < 64; ++cc) {
      float wv = WS[j * 65 + cc];
#pragma unroll
      for (int o = 0; o < 4; ++o) acc[o] += xS[(o * 4 + so) * 64 + cc] * wv;
    }
  }
#pragma unroll
  for (int o = 0; o < 4; ++o) qhS[(o * 4 + so) * 65 + j] = acc[o] * 0.125f;

  // ---- kh = km @ Wk.T ----
  acc[0] = acc[1] = acc[2] = acc[3] = 0.f;
  for (int c0 = 0; c0 < 512; c0 += 64) {
    __syncthreads();
#pragma unroll
    for (int p = 0; p < 4; ++p) {
      int r = p * 16 + (tid >> 4);
      int c4 = (tid & 15) * 4;
      float4 f = *(const float4*)&Wk[(size_t)(h * 64 + r) * 512 + c0 + c4];
      WS[r * 65 + c4 + 0] = f.x; WS[r * 65 + c4 + 1] = f.y;
      WS[r * 65 + c4 + 2] = f.z; WS[r * 65 + c4 + 3] = f.w;
    }
    {
      int s = tid >> 4;
      int c4 = (tid & 15) * 4;
      float4 f = *(const float4*)&km[(size_t)(b * 16 + s) * 512 + c0 + c4];
      xS[s * 64 + c4 + 0] = f.x; xS[s * 64 + c4 + 1] = f.y;
      xS[s * 64 + c4 + 2] = f.z; xS[s * 64 + c4 + 3] = f.w;
    }
    __syncthreads();
    for (int cc = 0; cc < 64; ++cc) {
      float wv = WS[j * 65 + cc];
#pragma unroll
      for (int o = 0; o < 4; ++o) acc[o] += xS[(o * 4 + so) * 64 + cc] * wv;
    }
  }
#pragma unroll
  for (int o = 0; o < 4; ++o) khS[(o * 4 + so) * 65 + j] = acc[o];
  __syncthreads();

  // logits + softmax (stored transposed: [t][s])
  {
    int s = tid >> 4, t = tid & 15;
    float a = 0.f;
    for (int jj = 0; jj < 64; ++jj) a += qhS[s * 65 + jj] * khS[t * 65 + jj];
    lg[s * 17 + t] = a;
  }
  __syncthreads();
  if (tid < 16) {
    int s = tid;
    float mx = -1e30f;
#pragma unroll
    for (int t = 0; t < 16; ++t) mx = fmaxf(mx, lg[s * 17 + t]);
    float e[16], sum = 0.f;
#pragma unroll
    for (int t = 0; t < 16; ++t) { e[t] = __expf(lg[s * 17 + t] - mx); sum += e[t]; }
    float inv = 1.0f / sum;
#pragma unroll
    for (int t = 0; t < 16; ++t)
      attnT[(blockIdx.x) * 256 + t * 16 + s] = e[t] * inv;
  }
}

// ---------------------------------------------------------------- k_gemm
// grid (8 p-tiles, 4 d-tiles, 64 bt) x 256. m97 structure: 128x128 tile, BK=32,
// 4 waves (2x2 of 64x64), 16x16x32 bf16 MFMA, global_load_lds 16B staging.
// VP[d][p] = sum_c Wv[d][c] * vT[p][c]  -> fp32 into d_out.
__global__ __launch_bounds__(256) void k_gemm(const unsigned short* __restrict__ Wv_bf,
                                              const unsigned short* __restrict__ vT,
                                              float* __restrict__ VP) {
  int tid = threadIdx.x;
  int bx = blockIdx.x, by = blockIdx.y, bz = blockIdx.z;
  __shared__ __align__(16) unsigned short As[128 * 32];
  __shared__ __align__(16) unsigned short Bs[128 * 32];
  const unsigned short* Ag = Wv_bf + (size_t)(by * 128) * 512;
  const unsigned short* Bg = vT + (size_t)bz * 524288 + (size_t)(bx * 128) * 512;
  int r = tid >> 2;           // 0..63 (staging row)
  int c8 = (tid & 3) * 8;     // k offset within BK=32
  int lane = tid & 63, wave = tid >> 6;
  int wd = wave >> 1, wm = wave & 1;
  int l15 = lane & 15, quad = lane >> 4;

  f32x4 acc[4][4];
#pragma unroll
  for (int i = 0; i < 4; ++i)
#pragma unroll
    for (int j = 0; j < 4; ++j) acc[i][j] = (f32x4){0.f, 0.f, 0.f, 0.f};

  for (int kk = 0; kk < 16; ++kk) {
    int c0 = kk * 32;
    if (kk) __syncthreads();
    __builtin_amdgcn_global_load_lds(
        (const __attribute__((address_space(1))) void*)(Ag + (size_t)r * 512 + c0 + c8),
        (__attribute__((address_space(3))) void*)&As[tid * 8], 16, 0, 0);
    __builtin_amdgcn_global_load_lds(
        (const __attribute__((address_space(1))) void*)(Ag + (size_t)(r + 64) * 512 + c0 + c8),
        (__attribute__((address_space(3))) void*)&As[2048 + tid * 8], 16, 0, 0);
    __builtin_amdgcn_global_load_lds(
        (const __attribute__((address_space(1))) void*)(Bg + (size_t)r * 512 + c0 + c8),
        (__attribute__((address_space(3))) void*)&Bs[tid * 8], 16, 0, 0);
    __builtin_amdgcn_global_load_lds(
        (const __attribute__((address_space(1))) void*)(Bg + (size_t)(r + 64) * 512 + c0 + c8),
        (__attribute__((address_space(3))) void*)&Bs[2048 + tid * 8], 16, 0, 0);
    __syncthreads();  // compiler drains vmcnt before s_barrier (m97-verified)

    bf16x8 af[4], bfr[4];
#pragma unroll
    for (int i = 0; i < 4; ++i)
      af[i] = *(const bf16x8*)&As[(wd * 64 + i * 16 + l15) * 32 + quad * 8];
#pragma unroll
    for (int j = 0; j < 4; ++j)
      bfr[j] = *(const bf16x8*)&Bs[(wm * 64 + j * 16 + l15) * 32 + quad * 8];
#pragma unroll
    for (int i = 0; i < 4; ++i)
#pragma unroll
      for (int j = 0; j < 4; ++j)
        acc[i][j] = __builtin_amdgcn_mfma_f32_16x16x32_bf16(af[i], bfr[j], acc[i][j], 0, 0, 0);
  }

  float* outp = VP + (size_t)bz * 524288;
#pragma unroll
  for (int i = 0; i < 4; ++i) {
#pragma unroll
    for (int j = 0; j < 4; ++j) {
      int m = bx * 128 + wm * 64 + j * 16 + l15;
#pragma unroll
      for (int rr = 0; rr < 4; ++rr) {
        int d = by * 128 + wd * 64 + i * 16 + quad * 4 + rr;  // C/D: row=quad*4+reg, col=lane&15
        outp[(size_t)d * 1024 + m] = acc[i][j][rr];
      }
    }
  }
}

// ---------------------------------------------------------------- k_mix (v3)
// grid 2048 (b*512+d) x 256. In-place on d_out, NO LDS, no transpose.
// Thread owns 4 contiguous pixels p0..p0+3 of column d: reads VP[t][d][p0..3]
// for t=0..15 (coalesced dwordx4), mixes with block-uniform attnT (s_load),
// writes out[s][d][p0..3] for s=0..15 (coalesced dwordx4). Per-thread the read
// and write address sets are identical and all loads precede all stores in
// program order -> in-place safe; disjoint across threads/blocks.
__global__ __launch_bounds__(256) void k_mix(float* __restrict__ out,
                                             const float* __restrict__ attnT) {
  int blk = blockIdx.x;
  int b = blk >> 9, d = blk & 511, h = d >> 6;
  int tid = threadIdx.x;
  const float* at = attnT + (b * 8 + h) * 256;  // [t][s]
  size_t base = ((size_t)(b * 16) * 512 + d) * 1024 + tid * 4;  // (b,t=0,d,p0)

  float res[16][4];
#pragma unroll
  for (int s = 0; s < 16; ++s)
#pragma unroll
    for (int j = 0; j < 4; ++j) res[s][j] = 0.f;

#pragma unroll
  for (int t = 0; t < 16; ++t) {
    float4 vp = *(const float4*)&out[base + (size_t)t * 524288];
#pragma unroll
    for (int s = 0; s < 16; ++s) {
      float a = at[t * 16 + s];  // uniform -> scalar load
      res[s][0] += a * vp.x; res[s][1] += a * vp.y;
      res[s][2] += a * vp.z; res[s][3] += a * vp.w;
    }
  }

#pragma unroll
  for (int s = 0; s < 16; ++s) {
    float4 f = {res[s][0], res[s][1], res[s][2], res[s][3]};
    *(float4*)&out[base + (size_t)s * 524288] = f;
  }
}

// ---------------------------------------------------------------- launch
extern "C" void kernel_launch(void* const* d_in, const int* in_sizes, int n_in,
                              void* d_out, int out_size, void* d_ws, size_t ws_size,
                              hipStream_t stream) {
  const float* q  = (const float*)d_in[0];
  const float* k  = (const float*)d_in[1];
  const float* v  = (const float*)d_in[2];
  const float* Wq = (const float*)d_in[3];
  const float* Wk = (const float*)d_in[4];
  const float* Wv = (const float*)d_in[5];
  // heads (d_in[6]) is the constant 8 — baked in.

  char* ws = (char*)d_ws;
  unsigned short* vT    = (unsigned short*)ws;                 // 67,108,864 B
  unsigned short* Wv_bf = (unsigned short*)(ws + 67108864);    //    524,288 B
  float* qm    = (float*)(ws + 67633152);                      //    131,072 B
  float* km    = (float*)(ws + 67764224);                      //    131,072 B
  float* attnT = (float*)(ws + 67895296);                      //     32,768 B
  float* out   = (float*)d_out;

  k_means<<<16384, 256, 0, stream>>>(q, k, qm, km);
  k_trans<<<dim3(16, 8, 64), 256, 0, stream>>>(v, vT);
  k_attn<<<32, 256, 0, stream>>>(qm, km, Wq, Wk, Wv, Wv_bf, attnT);
  k_gemm<<<dim3(8, 4, 64), 256, 0, stream>>>(Wv_bf, vT, out);
  k_mix<<<2048, 256, 0, stream>>>(out, attnT);
}